// Round 4
// baseline (315.928 us; speedup 1.0000x reference)
//
#include <hip/hip_runtime.h>

// Problem constants
#define B_SZ   64
#define IC_N   128
#define OC_N   128
#define OUT_D  1024
#define L_N    2048

typedef __attribute__((ext_vector_type(8))) __bf16 bf16x8;
typedef __attribute__((ext_vector_type(4))) float  f32x4;

// RNE fp32->bf16, packed pair (lo in low 16 bits).
__device__ __forceinline__ unsigned pack2bf(float lo, float hi) {
    unsigned ul = __builtin_bit_cast(unsigned, lo);
    unsigned uh = __builtin_bit_cast(unsigned, hi);
    ul += 0x7fffu + ((ul >> 16) & 1u);
    uh += 0x7fffu + ((uh >> 16) & 1u);
    return (ul >> 16) | (uh & 0xffff0000u);
}

// ======================= FUSED single-pass, 2 blocks/CU =====================
// Round-4 theory: round-3's register prefetch was collapsed by the compiler
// (VGPR=104 proves both load sets were never in flight); with 1 block/CU the
// collapsed vmcnt wait idles the whole CU -> 1.1 TB/s. Fix = TLP:
//   512 blocks x 512 threads, block = 64 b x 64 oc (och half) x 4 d.
//   LDS 2x32 KB -> 2 blocks/CU = 16 waves/CU in 2 INDEPENDENT barrier domains;
//   block B covers block A's stalls. acc 64->32 VGPR, fits 128-VGPR budget.
// x duplicated across och twins (+64 MB logical) but twin + dg-pair are on the
// SAME XCD under the swizzle -> L2 absorbs (FETCH ~unchanged is the check).
// Layouts/fragment mappings identical to the verified round-1 kernel.
__global__ __launch_bounds__(512, 4)
void lc1d_fused(const float* __restrict__ x, const float* __restrict__ w,
                float* __restrict__ out) {
    __shared__ __align__(16) unsigned smem[2][8192];   // 2 x 32 KB

    const int bid = blockIdx.x;                 // 0..511
    const int xcd = bid & 7;
    const int g   = bid >> 3;                   // 0..63
    const int dg  = xcd * 32 + (g & 31);        // 0..255, l-run = dg*8 .. +7
    const int och = g >> 5;                     // 0..1
    const int o0  = och * 64;

    const int t = threadIdx.x, wv = t >> 6, lane = t & 63;
    const int col = lane & 15, quad = lane >> 4;

    // staging coords: j = float4 half of 8-float l-run, icl = ic-in-chunk,
    // rb = row base (row = rb + 16r, r=0..3)
    const int j   = t & 1;
    const int icl = (t >> 1) & 15;
    const int rb  = t >> 5;                     // 0..15

    const float* xp = x + ((size_t)rb * IC_N + icl) * L_N + (size_t)dg * 8 + 4 * j;
    const float* wp = w + ((size_t)(o0 + rb) * IC_N + icl) * L_N + (size_t)dg * 8 + 4 * j;
    const size_t RS = (size_t)16 * IC_N * L_N;  // +16 rows (b or oc)
    const size_t CS = (size_t)16 * L_N;         // +16 ic (next chunk)

    // compute coords: wave -> (dl = d-local 0..3, bh = b-half 0..1)
    const int dl = wv & 3, bh = wv >> 2;
    const int xread = dl * 1024 + (bh * 32 + col) * 16 + quad * 4;   // +mt*256
    const int wread = 4096 + dl * 1024 + col * 16 + quad * 4;        // +nt*256

    f32x4 acc[2][4];
#pragma unroll
    for (int mt = 0; mt < 2; ++mt)
#pragma unroll
        for (int nt = 0; nt < 4; ++nt)
            acc[mt][nt] = (f32x4){0.f, 0.f, 0.f, 0.f};

    float4 xv[4], wvv[4];

    auto load_chunk = [&](int c) {
        const int cc = (c + xcd) & 7;           // per-XCD chunk stagger
        const float* xq = xp + (size_t)cc * CS;
        const float* wq = wp + (size_t)cc * CS;
#pragma unroll
        for (int r = 0; r < 4; ++r) xv[r]  = *(const float4*)(xq + (size_t)r * RS);
#pragma unroll
        for (int r = 0; r < 4; ++r) wvv[r] = *(const float4*)(wq + (size_t)r * RS);
    };

    auto store_slab = [&](int buf) {
        unsigned* Xs = smem[buf];               // [dl 4][b 64][icl 16] dwords
        unsigned* Ws = smem[buf] + 4096;        // [dl 4][oc 64][icl 16] dwords
#pragma unroll
        for (int r = 0; r < 4; ++r) {
            const int row = (rb + 16 * r) * 16 + icl;
            Xs[(2 * j) * 1024 + row]     = pack2bf(xv[r].x, xv[r].y);
            Xs[(2 * j + 1) * 1024 + row] = pack2bf(xv[r].z, xv[r].w);
        }
#pragma unroll
        for (int r = 0; r < 4; ++r) {
            const int row = (rb + 16 * r) * 16 + icl;
            Ws[(2 * j) * 1024 + row]     = pack2bf(wvv[r].x, wvv[r].y);
            Ws[(2 * j + 1) * 1024 + row] = pack2bf(wvv[r].z, wvv[r].w);
        }
    };

    auto compute = [&](int buf) {
        const unsigned* base = smem[buf];
        bf16x8 a[2], b[4];
#pragma unroll
        for (int mt = 0; mt < 2; ++mt)
            a[mt] = __builtin_bit_cast(bf16x8, *(const uint4*)(base + xread + mt * 256));
#pragma unroll
        for (int nt = 0; nt < 4; ++nt)
            b[nt] = __builtin_bit_cast(bf16x8, *(const uint4*)(base + wread + nt * 256));
#pragma unroll
        for (int mt = 0; mt < 2; ++mt)
#pragma unroll
            for (int nt = 0; nt < 4; ++nt)
                acc[mt][nt] = __builtin_amdgcn_mfma_f32_16x16x32_bf16(
                    a[mt], b[nt], acc[mt][nt], 0, 0, 0);
    };

    load_chunk(0);
#pragma unroll
    for (int c = 0; c < 8; ++c) {
        const int buf = c & 1;
        store_slab(buf);       // vmcnt wait lands here
        __syncthreads();       // one barrier per chunk (dbuf hazard-safe:
                               // buf's reads at iter c drain before any wave
                               // passes barrier c+1 and rewrites buf at c+2)
        if (c < 7) load_chunk(c + 1);
        compute(buf);
    }

    // ---- epilogue: LDS transpose (reuse smem, 20 KB) -> float4 d-run stores -
    const float scale = 0.088388347648318447f;  // 1/sqrt(128)
    float* ep = (float*)smem;                   // [b_l 16][o 64][dl 4 + pad 1]
#pragma unroll
    for (int r = 0; r < 4; ++r) {               // b-chunk of 16: bh=r>>1, mt=r&1
        __syncthreads();                        // prior smem reads done
        if (bh == (r >> 1)) {
            const int mt = r & 1;
#pragma unroll
            for (int nt = 0; nt < 4; ++nt)
#pragma unroll
                for (int reg = 0; reg < 4; ++reg) {
                    const int b_l = 4 * quad + reg;
                    const int o   = 16 * nt + col;
                    ep[(b_l * 64 + o) * 5 + dl] = acc[mt][nt][reg] * scale;
                }
        }
        __syncthreads();
#pragma unroll
        for (int pi = 0; pi < 2; ++pi) {
            const int P = t + 512 * pi;         // (b_l, o) pair, 0..1023
            const int b_l = P >> 6, o = P & 63;
            const float* s = &ep[(size_t)P * 5];
            float4 v;
            v.x = s[0]; v.y = s[1]; v.z = s[2]; v.w = s[3];
            *(float4*)&out[(size_t)((16 * r + b_l) * OC_N + o0 + o) * OUT_D + dg * 4] = v;
        }
    }
}

// ================================ launch ====================================
extern "C" void kernel_launch(void* const* d_in, const int* in_sizes, int n_in,
                              void* d_out, int out_size, void* d_ws, size_t ws_size,
                              hipStream_t stream) {
    const float* x = (const float*)d_in[0];
    const float* w = (const float*)d_in[1];
    float* out     = (float*)d_out;
    hipLaunchKernelGGL(lc1d_fused, dim3(512), dim3(512), 0, stream, x, w, out);
}

// Round 5
// 293.259 us; speedup vs baseline: 1.0773x; 1.0773x over previous
//
#include <hip/hip_runtime.h>

// Problem constants
#define B_SZ   64
#define IC_N   128
#define OC_N   128
#define OUT_D  1024
#define L_N    2048

typedef __attribute__((ext_vector_type(8))) __bf16 bf16x8;
typedef __attribute__((ext_vector_type(4))) float  f32x4;

// RNE fp32->bf16, packed pair (lo in low 16 bits).
__device__ __forceinline__ unsigned pack2bf(float lo, float hi) {
    unsigned ul = __builtin_bit_cast(unsigned, lo);
    unsigned uh = __builtin_bit_cast(unsigned, hi);
    ul += 0x7fffu + ((ul >> 16) & 1u);
    uh += 0x7fffu + ((uh >> 16) & 1u);
    return (ul >> 16) | (uh & 0xffff0000u);
}

// ======================= FUSED single-pass, hand-pipelined ==================
// r3 structure (256 blocks, 512 thr, 1 block/CU, 4 d x 64 b x 128 oc, dbuf LDS)
// with the load pipeline forced by hand (T4 counted-vmcnt, plain HIP + asm):
//  - 12 loads/chunk issued as asm volatile global_load_dwordx4: the compiler
//    cannot sink them (r3: VGPR=104 proved it collapsed the C-level prefetch)
//    and __syncthreads does NOT drain them (untracked by compiler vmcnt).
//  - 2 register sets (A/B) -> 24 loads permanently in flight (~25 MB GPU-wide
//    >> 6 MB bandwidth-delay product). Manual s_waitcnt vmcnt(12) per chunk
//    (vmcnt(0) only at the last), never a full drain in the main loop.
//  - sched_barrier(0) after each wait so ds_writes can't hoist above it
//    (guide rule #18); ds_write data-deps pin them after their load asm.
// Queue check: prologue 24 out; iter c: wait->12 (set c+1), pack(c),
// issue(c+2)->24, barrier, compute(c). c=7: wait vmcnt(0). Constant counts.
// LDS hazard proof unchanged from r3 (write->barrier->read same buf; reads
// drained by lgkmcnt(0) at the next barrier before the +2-chunk rewrite).
__global__ __launch_bounds__(512, 2)
void lc1d_fused(const float* __restrict__ x, const float* __restrict__ w,
                float* __restrict__ out) {
    __shared__ __align__(16) unsigned smem[2][12288];   // 2 x 48 KB

    const int bid = blockIdx.x;
    const int dg  = (bid & 7) * 32 + (bid >> 3);     // bijection on [0,256)
    const int phase = bid & 7;                       // constant per XCD
    const int t = threadIdx.x, wv = t >> 6, lane = t & 63;
    const int col = lane & 15, quad = lane >> 4;

    // staging coords
    const int j   = t & 1;
    const int icl = (t >> 1) & 15;
    const int rb  = t >> 5;                          // 0..15

    const float* xp = x + ((size_t)rb * IC_N + icl) * L_N + (size_t)dg * 8 + 4 * j;
    const float* wp = w + ((size_t)rb * IC_N + icl) * L_N + (size_t)dg * 8 + 4 * j;
    const size_t RS = (size_t)16 * IC_N * L_N;       // +16 rows (b or oc)
    const size_t CS = (size_t)16 * L_N;              // +16 ic (next chunk)

    // compute coords
    const int dl = wv & 3;
    const int xoff = dl * 1024 + col * 16 + quad * 4;
    const int woff = 4096 + dl * 2048 + ((wv >> 2) * 64 + col) * 16 + quad * 4;

    f32x4 acc[4][4];
#pragma unroll
    for (int mt = 0; mt < 4; ++mt)
#pragma unroll
        for (int nt = 0; nt < 4; ++nt)
            acc[mt][nt] = (f32x4){0.f, 0.f, 0.f, 0.f};

    // two register prefetch sets, pinned in flight via asm loads
    f32x4 xA[4], wA[8], xB[4], wB[8];

#define ISSUE_SET(XV, WV, c)                                                     \
    do {                                                                         \
        const int cc_ = ((c) + phase) & 7;                                       \
        const float* xq_ = xp + (size_t)cc_ * CS;                                \
        const float* wq_ = wp + (size_t)cc_ * CS;                                \
        _Pragma("unroll")                                                        \
        for (int r_ = 0; r_ < 4; ++r_)                                           \
            asm volatile("global_load_dwordx4 %0, %1, off"                       \
                         : "=v"(XV[r_]) : "v"(xq_ + (size_t)r_ * RS));           \
        _Pragma("unroll")                                                        \
        for (int r_ = 0; r_ < 8; ++r_)                                           \
            asm volatile("global_load_dwordx4 %0, %1, off"                       \
                         : "=v"(WV[r_]) : "v"(wq_ + (size_t)r_ * RS));           \
    } while (0)

    auto store_slab = [&](int buf, const f32x4* XV, const f32x4* WV) {
        unsigned* Xs = smem[buf];
        unsigned* Ws = smem[buf] + 4096;
#pragma unroll
        for (int r = 0; r < 4; ++r) {
            const int row = (rb + 16 * r) * 16 + icl;
            Xs[(2 * j) * 1024 + row]     = pack2bf(XV[r][0], XV[r][1]);
            Xs[(2 * j + 1) * 1024 + row] = pack2bf(XV[r][2], XV[r][3]);
        }
#pragma unroll
        for (int r = 0; r < 8; ++r) {
            const int row = (rb + 16 * r) * 16 + icl;
            Ws[(2 * j) * 2048 + row]     = pack2bf(WV[r][0], WV[r][1]);
            Ws[(2 * j + 1) * 2048 + row] = pack2bf(WV[r][2], WV[r][3]);
        }
    };

    auto compute = [&](int buf) {
        const unsigned* base = smem[buf];
        bf16x8 a[4], b[4];
#pragma unroll
        for (int mt = 0; mt < 4; ++mt)
            a[mt] = __builtin_bit_cast(bf16x8, *(const uint4*)(base + xoff + mt * 256));
#pragma unroll
        for (int nt = 0; nt < 4; ++nt)
            b[nt] = __builtin_bit_cast(bf16x8, *(const uint4*)(base + woff + nt * 256));
#pragma unroll
        for (int mt = 0; mt < 4; ++mt)
#pragma unroll
            for (int nt = 0; nt < 4; ++nt)
                acc[mt][nt] = __builtin_amdgcn_mfma_f32_16x16x32_bf16(
                    a[mt], b[nt], acc[mt][nt], 0, 0, 0);
    };

    // prologue: 2 sets (24 loads) in flight
    ISSUE_SET(xA, wA, 0);
    ISSUE_SET(xB, wB, 1);

#pragma unroll
    for (int c = 0; c < 8; ++c) {
        // wait for set c only; leave set c+1 (12 loads) in flight
        if (c < 7) asm volatile("s_waitcnt vmcnt(12)" ::: "memory");
        else       asm volatile("s_waitcnt vmcnt(0)"  ::: "memory");
        __builtin_amdgcn_sched_barrier(0);

        if (c & 1) store_slab(1, xB, wB);
        else       store_slab(0, xA, wA);

        // refill the just-consumed set with chunk c+2 (WAR deps keep order)
        if (c + 2 < 8) {
            if (c & 1) ISSUE_SET(xB, wB, c + 2);
            else       ISSUE_SET(xA, wA, c + 2);
        }

        __syncthreads();     // drains lgkm (ds_writes) but NOT the asm loads
        compute(c & 1);
    }
#undef ISSUE_SET

    // ---- epilogue: LDS transpose (reuse smem, 40 KB) -> float4 d-run stores -
    const float scale = 0.088388347648318447f;   // 1/sqrt(128)
    float* ep = (float*)smem;
    const int nh2 = wv >> 2;
#pragma unroll
    for (int r = 0; r < 4; ++r) {                // b-chunk of 16 (= mt tile r)
        __syncthreads();                         // prior smem reads done
#pragma unroll
        for (int nt = 0; nt < 4; ++nt)
#pragma unroll
            for (int reg = 0; reg < 4; ++reg) {
                const int b_l = 4 * quad + reg;
                const int o   = nh2 * 64 + 16 * nt + col;
                ep[(b_l * 128 + o) * 5 + dl] = acc[r][nt][reg] * scale;
            }
        __syncthreads();
#pragma unroll
        for (int pi = 0; pi < 4; ++pi) {
            const int P = t + 512 * pi;          // (b_l, o) pair, 0..2047
            const int b_l = P >> 7, o = P & 127;
            const float* s = &ep[(size_t)P * 5];
            float4 v;
            v.x = s[0]; v.y = s[1]; v.z = s[2]; v.w = s[3];
            *(float4*)&out[(size_t)((16 * r + b_l) * OC_N + o) * OUT_D + dg * 4] = v;
        }
    }
}

// ================================ launch ====================================
extern "C" void kernel_launch(void* const* d_in, const int* in_sizes, int n_in,
                              void* d_out, int out_size, void* d_ws, size_t ws_size,
                              hipStream_t stream) {
    const float* x = (const float*)d_in[0];
    const float* w = (const float*)d_in[1];
    float* out     = (float*)d_out;
    hipLaunchKernelGGL(lc1d_fused, dim3(256), dim3(512), 0, stream, x, w, out);
}